// Round 14
// baseline (53.360 us; speedup 1.0000x reference)
//
#include <hip/hip_runtime.h>
#include <hip/hip_bf16.h>

#define NE    16
#define INF   512
#define OUTF  512
#define NT    2048
#define OTILE 64          // out-cols per block (4 o-subtiles of 16)
#define TCH   32          // tokens per chunk (2 t-subtiles of 16)
#define NZ    2           // token-chunk split across blocks
#define WROWS OTILE
#define LSTRIDE 520       // LDS row stride in bf16 elems (512 + 8 pad = 1040 B)
#define REPS  5           // DIAGNOSTIC: split fixed+cold vs warm-marginal for staged kernel

#define SZ_W   (WROWS * LSTRIDE * 2)            // 66560 B
#define SZ_X   (TCH * LSTRIDE * 2)              // 33280 B
#define SZ_LST ((NT + TCH) * 4)                 // 8320 B
#define SMEM_BYTES (SZ_W + SZ_X + SZ_LST + 32)  // ~108 KB

typedef __attribute__((ext_vector_type(4))) float f32x4;
typedef __attribute__((ext_vector_type(8))) short bf16x8;
typedef __attribute__((ext_vector_type(4))) short bf16x4;

__device__ inline short f2bf(float f) {
    union { __hip_bfloat16 h; short s; } u;
    u.h = __float2bfloat16(f);
    return u.s;
}

__device__ inline bf16x4 cvt4(f32x4 v) {
    bf16x4 r;
    r[0] = f2bf(v[0]); r[1] = f2bf(v[1]); r[2] = f2bf(v[2]); r[3] = f2bf(v[3]);
    return r;
}

__global__ __launch_bounds__(512, 2)
void switch_linear_kernel(const float* __restrict__ x,
                          const int* __restrict__ idx,
                          const float* __restrict__ W,
                          const float* __restrict__ bias,
                          float* __restrict__ out)
{
    extern __shared__ char smem[];
    short* s_W    = (short*)smem;                      // [WROWS][LSTRIDE] bf16
    short* s_X    = (short*)(smem + SZ_W);             // [TCH][LSTRIDE] bf16
    int*   s_list = (int*)(smem + SZ_W + SZ_X);        // token list
    int*   s_wcnt = (int*)(smem + SZ_W + SZ_X + SZ_LST);

    const int b   = blockIdx.x;
    const int e   = b & 15;               // expert; all blocks of e on XCD e%8
    const int o0  = ((b >> 4) & 7) * OTILE;  // out-tile base (0..448)
    const int z   = b >> 7;               // token-chunk phase 0..1
    const int tid = threadIdx.x;
    const int lane = tid & 63;
    const int wid  = tid >> 6;            // 0..7

    // ---- Wave layout: 8 waves = 2 (token) x 4 (out) sub-tiles of 16 ----
    const int wt = wid >> 2;   // token sub-tile 0..1
    const int wo = wid & 3;    // out   sub-tile 0..3
    const int lr = lane & 15;  // fragment row/col
    const int q  = lane >> 4;  // quarter (k-group / acc row group)
    const int orow = o0 + wo * 16 + lr;
    const int slot = tid >> 4; // x-staging: 16 threads per token row
    const int sub  = tid & 15;

    for (int rep = 0; rep < REPS; ++rep) {
        // Compiler-opaque zero: forces genuine re-execution of all loads each rep
        int zz = 0;
        asm volatile("" : "+v"(zz));
        const float* xp = x + zz;
        const int*   ip = idx + zz;
        const float* Wp = W + zz;
        const float* bp = bias + zz;

        // ---- Phase A: idx loads (registers) ----
        int iv[4];
#pragma unroll
        for (int it = 0; it < 4; ++it)
            iv[it] = ip[wid * 256 + it * 64 + lane];

        // ---- Phase B: stage W tile -> LDS bf16, coalesced ----
        const float* wbase = Wp + ((size_t)e * OUTF + o0) * INF;
#pragma unroll
        for (int i = 0; i < 16; ++i) {
            const int li = tid + i * 512;            // f32x4 index, 0..8191
            f32x4 v = ((const f32x4*)wbase)[li];
            const int row = li >> 7;
            const int col = (li * 4) & 511;
            *(bf16x4*)(&s_W[row * LSTRIDE + col]) = cvt4(v);
        }

        // ---- Phase C: ballot-compaction token list ----
        unsigned long long masks[4];
        int wtot = 0;
#pragma unroll
        for (int it = 0; it < 4; ++it) {
            const unsigned long long mk = __ballot(iv[it] == e);
            masks[it] = mk;
            wtot += __popcll(mk);
        }
        if (lane == 0) s_wcnt[wid] = wtot;
        __syncthreads();                      // s_wcnt ready (s_W writes also done)
        int base = 0;
#pragma unroll
        for (int w = 0; w < 8; ++w) { int c = s_wcnt[w]; if (w < wid) base += c; }
        const int cnt = s_wcnt[0] + s_wcnt[1] + s_wcnt[2] + s_wcnt[3]
                      + s_wcnt[4] + s_wcnt[5] + s_wcnt[6] + s_wcnt[7];
        const unsigned long long below = (1ull << lane) - 1ull;
        int run = base;
#pragma unroll
        for (int it = 0; it < 4; ++it) {
            const unsigned long long mk = masks[it];
            if (mk & (1ull << lane))
                s_list[run + __popcll(mk & below)] = wid * 256 + it * 64 + lane;
            run += __popcll(mk);
        }
        const int cnt_pad = (cnt + TCH - 1) & ~(TCH - 1);
        for (int i = cnt + tid; i < cnt_pad; i += 512) s_list[i] = -1;
        __syncthreads();                      // s_list + s_W ready
        if (cnt == 0) continue;               // block-uniform

        // ---- W fragments from LDS ----
        bf16x8 bfr[16];
#pragma unroll
        for (int kk = 0; kk < 16; ++kk)
            bfr[kk] = *(const bf16x8*)(&s_W[(wo * 16 + lr) * LSTRIDE + kk * 32 + q * 8]);
        const float bv = bp[e * OUTF + orow];

        // ---- Phase D: this z-phase's 32-token chunks ----
        for (int cb = z * TCH; cb < cnt_pad; cb += NZ * TCH) {
            int tok_s = s_list[cb + slot];
            if (tok_s < 0) tok_s = 0;
            const f32x4* xr = (const f32x4*)(xp + (size_t)tok_s * INF);
#pragma unroll
            for (int i = 0; i < 8; ++i) {
                f32x4 v = xr[sub + i * 16];
                *(bf16x4*)(&s_X[slot * LSTRIDE + sub * 4 + i * 64]) = cvt4(v);
            }
            __syncthreads();                  // s_X ready

            f32x4 acc = {0.f, 0.f, 0.f, 0.f};
#pragma unroll
            for (int kk = 0; kk < 16; ++kk) {
                bf16x8 afr = *(const bf16x8*)(&s_X[(wt * 16 + lr) * LSTRIDE + kk * 32 + q * 8]);
                acc = __builtin_amdgcn_mfma_f32_16x16x32_bf16(afr, bfr[kk], acc, 0, 0, 0);
            }
#pragma unroll
            for (int j = 0; j < 4; ++j) {
                const int tok = s_list[cb + wt * 16 + q * 4 + j];
                if (tok >= 0) out[(size_t)tok * OUTF + orow] = acc[j] + bv;
            }
            __syncthreads();                  // all s_X reads done before next stage
        }
    }
}

extern "C" void kernel_launch(void* const* d_in, const int* in_sizes, int n_in,
                              void* d_out, int out_size, void* d_ws, size_t ws_size,
                              hipStream_t stream) {
    const float* x    = (const float*)d_in[0];
    const int*   idx  = (const int*)d_in[1];
    const float* W    = (const float*)d_in[2];
    const float* bias = (const float*)d_in[3];
    float* out = (float*)d_out;

    dim3 grid(NE * (OUTF / OTILE) * NZ);  // 16 x 8 x 2 = 256 blocks
    dim3 block(512);                      // 8 waves
    switch_linear_kernel<<<grid, block, SMEM_BYTES, stream>>>(x, idx, W, bias, out);
}

// Round 15
// 13.291 us; speedup vs baseline: 4.0148x; 4.0148x over previous
//
#include <hip/hip_runtime.h>
#include <hip/hip_bf16.h>

#define NE    16
#define INF   512
#define OUTF  512
#define NT    2048
#define OTILE 64          // out-cols per block (4 o-subtiles of 16)
#define TCH   32          // tokens per chunk (2 t-subtiles of 16)
#define NZ    2           // token-chunk split across blocks
#define WROWS OTILE
#define LSTRIDE 520       // LDS row stride in bf16 elems (512 + 8 pad = 1040 B)

#define SZ_W   (WROWS * LSTRIDE * 2)            // 66560 B
#define SZ_X   (TCH * LSTRIDE * 2)              // 33280 B
#define SZ_LST ((NT + TCH) * 4)                 // 8320 B
#define SMEM_BYTES (SZ_W + SZ_X + SZ_LST + 32)  // ~108 KB

typedef __attribute__((ext_vector_type(4))) float f32x4;
typedef __attribute__((ext_vector_type(8))) short bf16x8;
typedef __attribute__((ext_vector_type(4))) short bf16x4;

__device__ inline short f2bf(float f) {
    union { __hip_bfloat16 h; short s; } u;
    u.h = __float2bfloat16(f);
    return u.s;
}

__device__ inline bf16x4 cvt4(f32x4 v) {
    bf16x4 r;
    r[0] = f2bf(v[0]); r[1] = f2bf(v[1]); r[2] = f2bf(v[2]); r[3] = f2bf(v[3]);
    return r;
}

__global__ __launch_bounds__(512, 2)
void switch_linear_kernel(const float* __restrict__ x,
                          const int* __restrict__ idx,
                          const float* __restrict__ W,
                          const float* __restrict__ bias,
                          float* __restrict__ out)
{
    extern __shared__ char smem[];
    short* s_W    = (short*)smem;                      // [WROWS][LSTRIDE] bf16
    short* s_X    = (short*)(smem + SZ_W);             // [TCH][LSTRIDE] bf16
    int*   s_list = (int*)(smem + SZ_W + SZ_X);        // token list
    int*   s_wcnt = (int*)(smem + SZ_W + SZ_X + SZ_LST);

    const int b   = blockIdx.x;
    const int e   = b & 15;               // expert; all blocks of e on XCD e%8
    const int oj  = (b >> 4) & 7;         // o-tile index (stagger phase)
    const int o0  = oj * OTILE;           // out-tile base (0..448)
    const int z   = b >> 7;               // token-chunk phase 0..1
    const int tid = threadIdx.x;
    const int lane = tid & 63;
    const int wid  = tid >> 6;            // 0..7

    // ---- Phase A: idx loads (registers) ----
    int iv[4];
#pragma unroll
    for (int it = 0; it < 4; ++it)
        iv[it] = idx[wid * 256 + it * 64 + lane];

    // ---- Phase B: stage W tile -> LDS bf16, coalesced.
    // z-pair blocks share this tile; stage halves in OPPOSITE order so each
    // 64KB half is fabric-fetched once and L2-hit by the partner. ----
    const float* wbase = W + ((size_t)e * OUTF + o0) * INF;  // 64 rows x 512
#pragma unroll
    for (int i = 0; i < 16; ++i) {
        const int ii = z ? ((i + 8) & 15) : i;   // z=1 starts at second half
        const int li = tid + ii * 512;           // f32x4 index, 0..8191
        f32x4 v = ((const f32x4*)wbase)[li];
        const int row = li >> 7;
        const int col = (li * 4) & 511;
        *(bf16x4*)(&s_W[row * LSTRIDE + col]) = cvt4(v);
    }

    // ---- Phase C: ballot-compaction token list (no atomics, deterministic) ----
    unsigned long long masks[4];
    int wtot = 0;
#pragma unroll
    for (int it = 0; it < 4; ++it) {
        const unsigned long long mk = __ballot(iv[it] == e);
        masks[it] = mk;
        wtot += __popcll(mk);
    }
    if (lane == 0) s_wcnt[wid] = wtot;
    __syncthreads();                      // s_wcnt ready (s_W writes also done)
    int base = 0;
#pragma unroll
    for (int w = 0; w < 8; ++w) { int c = s_wcnt[w]; if (w < wid) base += c; }
    const int cnt = s_wcnt[0] + s_wcnt[1] + s_wcnt[2] + s_wcnt[3]
                  + s_wcnt[4] + s_wcnt[5] + s_wcnt[6] + s_wcnt[7];
    const unsigned long long below = (1ull << lane) - 1ull;
    int run = base;
#pragma unroll
    for (int it = 0; it < 4; ++it) {
        const unsigned long long mk = masks[it];
        if (mk & (1ull << lane))
            s_list[run + __popcll(mk & below)] = wid * 256 + it * 64 + lane;
        run += __popcll(mk);
    }
    const int cnt_pad = (cnt + TCH - 1) & ~(TCH - 1);
    for (int i = cnt + tid; i < cnt_pad; i += 512) s_list[i] = -1;
    __syncthreads();                      // s_list + s_W ready
    if (cnt == 0) return;                 // block-uniform

    // ---- Wave layout: 8 waves = 2 (token) x 4 (out) sub-tiles of 16 ----
    const int wt = wid >> 2;   // token sub-tile 0..1
    const int wo = wid & 3;    // out   sub-tile 0..3
    const int lr = lane & 15;  // fragment row/col
    const int q  = lane >> 4;  // quarter (k-group / acc row group)
    const int orow = o0 + wo * 16 + lr;

    // ---- W fragments from LDS (b128 reads, bank-spread by +16B pad) ----
    bf16x8 bfr[16];
#pragma unroll
    for (int kk = 0; kk < 16; ++kk)
        bfr[kk] = *(const bf16x8*)(&s_W[(wo * 16 + lr) * LSTRIDE + kk * 32 + q * 8]);
    const float bv = bias[e * OUTF + orow];

    // x-staging thread mapping: 16 threads per token row (32 rows)
    const int slot = tid >> 4;            // 0..31
    const int sub  = tid & 15;

    // ---- Phase D: this z-phase's chunks, STAGGERED by o-tile index so
    // same-expert blocks read different chunks at any instant (L2 reuse) ----
    const int M = (cnt_pad - z * TCH + (NZ * TCH) - 1) / (NZ * TCH);
    if (M > 0) {
        int m0 = oj % M;
        for (int k = 0; k < M; ++k) {
            int m = m0 + k; if (m >= M) m -= M;
            const int cb = z * TCH + m * (NZ * TCH);

            int tok_s = s_list[cb + slot];
            if (tok_s < 0) tok_s = 0;
            const f32x4* xr = (const f32x4*)(x + (size_t)tok_s * INF);
#pragma unroll
            for (int i = 0; i < 8; ++i) {
                f32x4 v = xr[sub + i * 16];
                *(bf16x4*)(&s_X[slot * LSTRIDE + sub * 4 + i * 64]) = cvt4(v);
            }
            __syncthreads();                  // s_X ready

            f32x4 acc = {0.f, 0.f, 0.f, 0.f};
#pragma unroll
            for (int kk = 0; kk < 16; ++kk) {
                bf16x8 afr = *(const bf16x8*)(&s_X[(wt * 16 + lr) * LSTRIDE + kk * 32 + q * 8]);
                acc = __builtin_amdgcn_mfma_f32_16x16x32_bf16(afr, bfr[kk], acc, 0, 0, 0);
            }
            // ---- Epilogue: D row = q*4+j (token), col = lr (out) ----
#pragma unroll
            for (int j = 0; j < 4; ++j) {
                const int tok = s_list[cb + wt * 16 + q * 4 + j];
                if (tok >= 0) out[(size_t)tok * OUTF + orow] = acc[j] + bv;
            }
            __syncthreads();                  // all s_X reads done before next stage
        }
    }
}

extern "C" void kernel_launch(void* const* d_in, const int* in_sizes, int n_in,
                              void* d_out, int out_size, void* d_ws, size_t ws_size,
                              hipStream_t stream) {
    const float* x    = (const float*)d_in[0];
    const int*   idx  = (const int*)d_in[1];
    const float* W    = (const float*)d_in[2];
    const float* bias = (const float*)d_in[3];
    float* out = (float*)d_out;

    dim3 grid(NE * (OUTF / OTILE) * NZ);  // 16 x 8 x 2 = 256 blocks
    dim3 block(512);                      // 8 waves
    switch_linear_kernel<<<grid, block, SMEM_BYTES, stream>>>(x, idx, W, bias, out);
}